// Round 6
// baseline (248.588 us; speedup 1.0000x reference)
//
#include <hip/hip_runtime.h>
#include <math.h>

#define N_TOK 16384
#define HDIM  2048
#define NEXP  64
#define TOPK  8
#define NKS   4             // K split factor
#define KSEG  (HDIM / NKS)  // 512 k per block
#define KCH   64            // k-chunk staged in LDS
#define NCH   (KSEG / KCH)  // 8
#define TTOK  256           // tokens per block (4 groups of 64)

// d_ws layout:
//   [0, 32 MiB)       : part  — partial logits f64 [NKS][N_TOK][64]
//   [32 MiB, 33 MiB)  : Wd    — weight as f64 [64][2048]
//   [33 MiB, ...)     : stats — f32 probsum[64], counts[64]
#define PART_OFF  0
#define WD_OFF    (32u << 20)
#define STATS_OFF (33u << 20)

__global__ __launch_bounds__(256) void conv_w_kernel(const float* __restrict__ W,
                                                     double* __restrict__ Wd) {
    int i = blockIdx.x * 256 + threadIdx.x;          // grid 512*256 = 131072
    Wd[i] = (double)W[i];
}

// GEMM partial, VALU f64 (proven path). Block = 512 thr (8 waves).
// Wave w -> experts [8w, 8w+8); lane = token%64; 4 token-groups per wave
// (tokens tg*64+lane) -> each s_load'ed weight feeds 4 FMAs (scalar-feed
// demand 2 B/cyc/CU, under the ~3.3 measured ceiling).
// Tile: 256 tokens x 64 experts x 512 k. Grid: 64 token-tiles x 4 K-segs.
__global__ __launch_bounds__(512, 2) void gemm_part_kernel(const float* __restrict__ X,
                                                           const double* __restrict__ Wd,
                                                           double* __restrict__ part) {
    const int tt  = blockIdx.x >> 2;
    const int ks  = blockIdx.x & 3;
    const int tid = threadIdx.x;
    const int tl  = tid & 63;                        // token lane
    const int e0  = __builtin_amdgcn_readfirstlane((tid >> 6) * 8);  // wave-uniform
    const int tok0 = tt * TTOK;
    const int k0   = ks * KSEG;

    __shared__ float xs[TTOK][68];                   // 64 cols + pad 4 (2-way = free)

    double acc[8][4];
#pragma unroll
    for (int e = 0; e < 8; ++e)
#pragma unroll
        for (int tg = 0; tg < 4; ++tg) acc[e][tg] = 0.0;

    // staging: 512 thr cover [256 rows][64 k] per chunk; thread -> rows sr+32j, cols sc..sc+3
    const int sr = tid >> 4;                         // 0..31
    const int sc = (tid & 15) * 4;                   // 0..60
    const float* xg = X + (size_t)(tok0 + sr) * HDIM + k0 + sc;

    float4 pf[8];
#pragma unroll
    for (int j = 0; j < 8; ++j)
        pf[j] = *(const float4*)(xg + (size_t)(32 * j) * HDIM);

    for (int c = 0; c < NCH; ++c) {
        __syncthreads();                             // readers of previous chunk done
#pragma unroll
        for (int j = 0; j < 8; ++j)
            *(float4*)&xs[sr + 32 * j][sc] = pf[j];
        __syncthreads();
        if (c + 1 < NCH) {                           // prefetch next chunk into regs
#pragma unroll
            for (int j = 0; j < 8; ++j)
                pf[j] = *(const float4*)(xg + (size_t)(32 * j) * HDIM + (c + 1) * KCH);
        }
        const double* wp = Wd + (size_t)e0 * HDIM + k0 + c * KCH;   // uniform -> s_load
#pragma unroll
        for (int kk = 0; kk < KCH / 4; ++kk) {
            double xv[4][4];
#pragma unroll
            for (int tg = 0; tg < 4; ++tg) {
                float4 xf = *(const float4*)&xs[tg * 64 + tl][kk * 4];
                xv[tg][0] = (double)xf.x; xv[tg][1] = (double)xf.y;
                xv[tg][2] = (double)xf.z; xv[tg][3] = (double)xf.w;
            }
#pragma unroll
            for (int e = 0; e < 8; ++e) {
                const double* w4 = wp + (size_t)e * HDIM + kk * 4;
                double w0 = w4[0], w1 = w4[1], w2 = w4[2], w3 = w4[3];
#pragma unroll
                for (int tg = 0; tg < 4; ++tg) {
                    acc[e][tg] = fma(xv[tg][0], w0, acc[e][tg]);
                    acc[e][tg] = fma(xv[tg][1], w1, acc[e][tg]);
                    acc[e][tg] = fma(xv[tg][2], w2, acc[e][tg]);
                    acc[e][tg] = fma(xv[tg][3], w3, acc[e][tg]);
                }
            }
        }
    }

#pragma unroll
    for (int tg = 0; tg < 4; ++tg) {
        double* pb = part + ((size_t)ks * N_TOK + tok0 + tg * 64 + tl) * NEXP + e0;
#pragma unroll
        for (int e = 0; e < 8; e += 2) {
            double2 v; v.x = acc[e][tg]; v.y = acc[e + 1][tg];
            *(double2*)(pb + e) = v;
        }
    }
}

// Top-k: stage 32 tokens' scores into LDS via fully-coalesced partial reads,
// then the PROVEN argmax ladder (f32 score comparator, ties -> lower index).
// Block = 256 thr (4 waves x 8 tokens); grid 512.
__global__ __launch_bounds__(256) void topk_kernel(const double* __restrict__ part,
                                                   float* __restrict__ outIdx,
                                                   float* __restrict__ outW,
                                                   float* __restrict__ stats) {
    __shared__ float sc_s[32][65];
    __shared__ float lds_counts[NEXP];
    __shared__ float psum_part[4][NEXP];
    const int tid  = threadIdx.x;
    const int lane = tid & 63;
    const int w    = tid >> 6;
    if (tid < NEXP) lds_counts[tid] = 0.f;

    const int t0 = blockIdx.x * 32;
    // stage scores: flat (tok,e) pairs, consecutive tid -> consecutive addresses
#pragma unroll
    for (int p = 0; p < 8; ++p) {
        const int idx = p * 256 + tid;               // 0..2047
        const int t   = idx >> 6;
        const int e   = idx & 63;
        const double* pp = part + ((size_t)(t0 + t)) * NEXP + e;
        double l = (pp[0] + pp[(size_t)N_TOK * NEXP]) +
                   (pp[2 * (size_t)N_TOK * NEXP] + pp[3 * (size_t)N_TOK * NEXP]);
        sc_s[t][e] = (float)(1.0 / (1.0 + exp(-l))); // one rounding to f32
    }
    __syncthreads();

    float ps = 0.f;
    for (int i = 0; i < 8; ++i) {
        const int tloc = w * 8 + i;
        const int t    = t0 + tloc;
        float s = sc_s[tloc][lane];

        float rs = s;
#pragma unroll
        for (int off = 32; off; off >>= 1) rs += __shfl_xor(rs, off);
        ps += s / (rs + 1e-9f);

        float cur = s;                                // masked working copy
        float denom = 0.f;
        int   wi = 0;
        float wv = 0.f;
#pragma unroll
        for (int k = 0; k < TOPK; ++k) {
            float m = cur; int mi = lane;
#pragma unroll
            for (int off = 32; off; off >>= 1) {      // argmax, ties -> min idx
                float om = __shfl_xor(m, off);
                int   oi = __shfl_xor(mi, off);
                if (om > m || (om == m && oi < mi)) { m = om; mi = oi; }
            }
            denom += m;
            if (lane == k)  { wi = mi; wv = m; }
            if (lane == mi) cur = -1e30f;             // mask winner
        }
        if (lane < TOPK) {
            outIdx[(size_t)t * TOPK + lane] = (float)wi;
            outW  [(size_t)t * TOPK + lane] = wv / (denom + 1e-9f);
            atomicAdd(&lds_counts[wi], 1.f);
        }
    }
    psum_part[w][lane] = ps;
    __syncthreads();
    if (tid < NEXP) {
        float tot = psum_part[0][tid] + psum_part[1][tid] +
                    psum_part[2][tid] + psum_part[3][tid];
        atomicAdd(&stats[tid], tot);                  // probsum
        atomicAdd(&stats[NEXP + tid], lds_counts[tid]); // counts
    }
}

__global__ void aux_kernel(const float* __restrict__ stats, float* __restrict__ out) {
    const int e = threadIdx.x;                        // 64 threads
    float prob = stats[e] / (float)N_TOK;
    float cnt  = stats[NEXP + e];
    float loadf = cnt / ((float)N_TOK * TOPK);
    float S = prob;
#pragma unroll
    for (int off = 32; off; off >>= 1) S += __shfl_xor(S, off);
    float pn = prob / (S + 1e-9f);
    float v  = loadf * pn;
#pragma unroll
    for (int off = 32; off; off >>= 1) v += __shfl_xor(v, off);
    if (e == 0) out[2 * N_TOK * TOPK] = 0.001f * v * (float)NEXP;
}

extern "C" void kernel_launch(void* const* d_in, const int* in_sizes, int n_in,
                              void* d_out, int out_size, void* d_ws, size_t ws_size,
                              hipStream_t stream) {
    (void)in_sizes; (void)n_in; (void)out_size; (void)ws_size;
    const float* X = (const float*)d_in[0];
    const float* W = (const float*)d_in[1];
    float* out = (float*)d_out;
    char*  ws  = (char*)d_ws;
    double* part  = (double*)(ws + PART_OFF);
    double* Wd    = (double*)(ws + WD_OFF);
    float*  stats = (float*)(ws + STATS_OFF);

    hipMemsetAsync(stats, 0, 128 * sizeof(float), stream);
    conv_w_kernel<<<512, 256, 0, stream>>>(W, Wd);
    gemm_part_kernel<<<256, 512, 0, stream>>>(X, Wd, part);
    topk_kernel<<<512, 256, 0, stream>>>(part, out, out + N_TOK * TOPK, stats);
    aux_kernel<<<1, 64, 0, stream>>>(stats, out);
}

// Round 7
// 225.683 us; speedup vs baseline: 1.1015x; 1.1015x over previous
//
#include <hip/hip_runtime.h>
#include <math.h>

#define N_TOK 16384
#define HDIM  2048
#define NEXP  64
#define TOPK  8
#define NKS   4             // K split factor
#define KSEG  (HDIM / NKS)  // 512 k per block
#define KCH   16            // k-chunk staged in LDS
#define NCH   (KSEG / KCH)  // 32
#define TTOK  64            // tokens per block

// d_ws layout:
//   [0, 32 MiB)       : part  — partial logits f64 [NKS][N_TOK][64]
//   [32 MiB, 33 MiB)  : Wt    — weight transposed f64 [2048 k][64 e]
//   [33 MiB, ...)     : stats — f32 probsum[64], counts[64]
#define PART_OFF  0
#define WT_OFF    (32u << 20)
#define STATS_OFF (33u << 20)

// Wt[k][e] = (double)W[e][k]; writes coalesced, reads L2-cached.
__global__ __launch_bounds__(256) void conv_wt_kernel(const float* __restrict__ W,
                                                      double* __restrict__ Wt) {
    int i = blockIdx.x * 256 + threadIdx.x;          // grid 512*256 = 131072
    int k = i >> 6, e = i & 63;
    Wt[i] = (double)W[(size_t)e * HDIM + k];
}

// GEMM partial, lane = EXPERT. Block = 512 thr (8 waves); wave wv owns tokens
// [8wv, 8wv+8); every lane computes its expert's logit for those tokens.
// W: f64 in VGPRs (from LDS, staged coalesced from Wt) — no scalar feed.
// X: f64 in LDS (converted once at staging), broadcast reads (uniform addr).
// VALU = pure f64 FMA. Tile: 64 tok x 64 exp x 512 k. Grid: 256 tt x 4 ks.
__global__ __launch_bounds__(512, 4) void gemm_part_kernel(const float* __restrict__ X,
                                                           const double* __restrict__ Wt,
                                                           double* __restrict__ part) {
    const int tt   = blockIdx.x >> 2;
    const int ks   = blockIdx.x & 3;
    const int tid  = threadIdx.x;
    const int lane = tid & 63;                       // expert
    const int wv   = tid >> 6;                       // 0..7
    const int tok0 = tt * TTOK;
    const int k0   = ks * KSEG;

    __shared__ double xs[TTOK][KCH + 2];             // 64 x 18 f64 (16B-aligned rows)
    __shared__ double wsh[KCH][NEXP + 2];            // 16 x 66 f64

    double acc[8];
#pragma unroll
    for (int t = 0; t < 8; ++t) acc[t] = 0.0;

    // X staging: 8 thr per token row, float2 each (64B/row, coalesced)
    const int sx_tok = tid >> 3;                     // 0..63
    const int sx_k   = (tid & 7) * 2;                // 0,2..14
    const float* xg  = X + (size_t)(tok0 + sx_tok) * HDIM + k0 + sx_k;
    // W staging: double2 per thread from Wt (fully coalesced)
    const int sw_k = tid >> 5;                       // 0..15
    const int sw_e = (tid & 31) * 2;                 // 0..62
    const double* wg = Wt + (size_t)(k0 + sw_k) * NEXP + sw_e;

    float2  px = *(const float2*)xg;
    double2 pw = *(const double2*)wg;

    for (int c = 0; c < NCH; ++c) {
        __syncthreads();                             // readers of previous chunk done
        {
            double2 xv; xv.x = (double)px.x; xv.y = (double)px.y;
            *(double2*)&xs[sx_tok][sx_k] = xv;       // one cvt per element per block
            *(double2*)&wsh[sw_k][sw_e]  = pw;
        }
        __syncthreads();
        if (c + 1 < NCH) {                           // prefetch next chunk into regs
            px = *(const float2*)(xg + (c + 1) * KCH);
            pw = *(const double2*)(wg + (size_t)(c + 1) * KCH * NEXP);
        }
        // W chunk -> VGPRs (per-lane expert column)
        double wr[KCH];
#pragma unroll
        for (int j = 0; j < KCH; ++j) wr[j] = wsh[j][lane];
        // tokens: X via LDS broadcast (uniform addr), pure f64 FMA
#pragma unroll
        for (int t = 0; t < 8; ++t) {
            const int tr = wv * 8 + t;
#pragma unroll
            for (int kp = 0; kp < KCH / 2; ++kp) {
                double2 xv = *(const double2*)&xs[tr][kp * 2];
                acc[t] = fma(xv.x, wr[kp * 2],     acc[t]);
                acc[t] = fma(xv.y, wr[kp * 2 + 1], acc[t]);
            }
        }
    }

    // epilogue: per token, 64 lanes write 64 consecutive doubles (512B lines)
    double* pb = part + ((size_t)ks * N_TOK + tok0 + wv * 8) * NEXP + lane;
#pragma unroll
    for (int t = 0; t < 8; ++t)
        pb[(size_t)t * NEXP] = acc[t];
}

// Top-k: stage 32 tokens' scores into LDS via fully-coalesced partial reads,
// then the PROVEN argmax ladder (f32 score comparator, ties -> lower index).
// Block = 256 thr (4 waves x 8 tokens); grid 512.
__global__ __launch_bounds__(256) void topk_kernel(const double* __restrict__ part,
                                                   float* __restrict__ outIdx,
                                                   float* __restrict__ outW,
                                                   float* __restrict__ stats) {
    __shared__ float sc_s[32][65];
    __shared__ float lds_counts[NEXP];
    __shared__ float psum_part[4][NEXP];
    const int tid  = threadIdx.x;
    const int lane = tid & 63;
    const int w    = tid >> 6;
    if (tid < NEXP) lds_counts[tid] = 0.f;

    const int t0 = blockIdx.x * 32;
#pragma unroll
    for (int p = 0; p < 8; ++p) {
        const int idx = p * 256 + tid;               // 0..2047
        const int t   = idx >> 6;
        const int e   = idx & 63;
        const double* pp = part + ((size_t)(t0 + t)) * NEXP + e;
        double l = (pp[0] + pp[(size_t)N_TOK * NEXP]) +
                   (pp[2 * (size_t)N_TOK * NEXP] + pp[3 * (size_t)N_TOK * NEXP]);
        sc_s[t][e] = (float)(1.0 / (1.0 + exp(-l))); // one rounding to f32
    }
    __syncthreads();

    float ps = 0.f;
    for (int i = 0; i < 8; ++i) {
        const int tloc = w * 8 + i;
        const int t    = t0 + tloc;
        float s = sc_s[tloc][lane];

        float rs = s;
#pragma unroll
        for (int off = 32; off; off >>= 1) rs += __shfl_xor(rs, off);
        ps += s / (rs + 1e-9f);

        float cur = s;                                // masked working copy
        float denom = 0.f;
        int   wi = 0;
        float wv = 0.f;
#pragma unroll
        for (int k = 0; k < TOPK; ++k) {
            float m = cur; int mi = lane;
#pragma unroll
            for (int off = 32; off; off >>= 1) {      // argmax, ties -> min idx
                float om = __shfl_xor(m, off);
                int   oi = __shfl_xor(mi, off);
                if (om > m || (om == m && oi < mi)) { m = om; mi = oi; }
            }
            denom += m;
            if (lane == k)  { wi = mi; wv = m; }
            if (lane == mi) cur = -1e30f;             // mask winner
        }
        if (lane < TOPK) {
            outIdx[(size_t)t * TOPK + lane] = (float)wi;
            outW  [(size_t)t * TOPK + lane] = wv / (denom + 1e-9f);
            atomicAdd(&lds_counts[wi], 1.f);
        }
    }
    psum_part[w][lane] = ps;
    __syncthreads();
    if (tid < NEXP) {
        float tot = psum_part[0][tid] + psum_part[1][tid] +
                    psum_part[2][tid] + psum_part[3][tid];
        atomicAdd(&stats[tid], tot);                  // probsum
        atomicAdd(&stats[NEXP + tid], lds_counts[tid]); // counts
    }
}

__global__ void aux_kernel(const float* __restrict__ stats, float* __restrict__ out) {
    const int e = threadIdx.x;                        // 64 threads
    float prob = stats[e] / (float)N_TOK;
    float cnt  = stats[NEXP + e];
    float loadf = cnt / ((float)N_TOK * TOPK);
    float S = prob;
#pragma unroll
    for (int off = 32; off; off >>= 1) S += __shfl_xor(S, off);
    float pn = prob / (S + 1e-9f);
    float v  = loadf * pn;
#pragma unroll
    for (int off = 32; off; off >>= 1) v += __shfl_xor(v, off);
    if (e == 0) out[2 * N_TOK * TOPK] = 0.001f * v * (float)NEXP;
}

extern "C" void kernel_launch(void* const* d_in, const int* in_sizes, int n_in,
                              void* d_out, int out_size, void* d_ws, size_t ws_size,
                              hipStream_t stream) {
    (void)in_sizes; (void)n_in; (void)out_size; (void)ws_size;
    const float* X = (const float*)d_in[0];
    const float* W = (const float*)d_in[1];
    float* out = (float*)d_out;
    char*  ws  = (char*)d_ws;
    double* part  = (double*)(ws + PART_OFF);
    double* Wt    = (double*)(ws + WT_OFF);
    float*  stats = (float*)(ws + STATS_OFF);

    hipMemsetAsync(stats, 0, 128 * sizeof(float), stream);
    conv_wt_kernel<<<512, 256, 0, stream>>>(W, Wt);
    gemm_part_kernel<<<1024, 512, 0, stream>>>(X, Wt, part);
    topk_kernel<<<512, 256, 0, stream>>>(part, out, out + N_TOK * TOPK, stats);
    aux_kernel<<<1, 64, 0, stream>>>(stats, out);
}